// Round 2
// baseline (6066.356 us; speedup 1.0000x reference)
//
#include <hip/hip_runtime.h>
#include <math.h>

#define NPTS 8192
#define CHN 128
#define NLAYER 12

// ---------------- weight transpose: Wt[l][c][o] = W[l][o][c], l<12:W1, l>=12:W2 ----
__global__ void transpose_w_kernel(const float* __restrict__ W1s,
                                   const float* __restrict__ W2s,
                                   float* __restrict__ Wt) {
  int idx = blockIdx.x * 256 + threadIdx.x;
  if (idx >= 24 * 128 * 128) return;
  int l = idx >> 14;
  int rem = idx & 16383;
  int o = rem & 127;
  int c = rem >> 7;
  const float* src = (l < 12) ? (W1s + ((size_t)l << 14)) : (W2s + ((size_t)(l - 12) << 14));
  Wt[idx] = src[o * 128 + c];
}

// ---------------- fused MLP + weighted Gram partials (deterministic) ----------------
__global__ __launch_bounds__(256, 2) void mlp_xwx_kernel(
    const float* __restrict__ xc,      // (B,4,N)
    const float* __restrict__ Wfirst,  // (128,4)
    const float* __restrict__ bfirst,  // (128)
    const float* __restrict__ Wt,      // (24,128,128) transposed [c][o]
    const float* __restrict__ b1s,     // (12,128)
    const float* __restrict__ b2s,     // (12,128)
    const float* __restrict__ Wfinal,  // (128)
    const float* __restrict__ bfinal,  // (1)
    float* __restrict__ partial) {     // (8192,45) per-block partials
  __shared__ float Hs[CHN][64];
  __shared__ float Ys[CHN][64];
  __shared__ float red[4][64];
  const int lane = threadIdx.x & 63;
  const int wv = threadIdx.x >> 6;
  const int o0 = __builtin_amdgcn_readfirstlane(wv << 5);  // wave-uniform out-ch base
  const int b = blockIdx.x >> 7;
  const int n0 = (blockIdx.x & 127) << 6;
  const float* xb = xc + ((size_t)b * 4) * NPTS + n0 + lane;
  const float x1 = xb[0 * NPTS];
  const float x2 = xb[1 * NPTS];
  const float y1 = xb[2 * NPTS];
  const float y2 = xb[3 * NPTS];

  #pragma unroll
  for (int j = 0; j < 32; ++j) {
    int o = o0 + j;
    float h = bfirst[o] + Wfirst[o * 4 + 0] * x1 + Wfirst[o * 4 + 1] * x2 +
              Wfirst[o * 4 + 2] * y1 + Wfirst[o * 4 + 3] * y2;
    Hs[o][lane] = h;
  }
  __syncthreads();

  for (int layer = 0; layer < NLAYER; ++layer) {
    const float* W1t = Wt + (size_t)layer * CHN * CHN;
    const float* W2t = Wt + (size_t)(layer + 12) * CHN * CHN;
    const float* b1 = b1s + layer * CHN;
    const float* b2 = b2s + layer * CHN;
    float acc[32];
    #pragma unroll
    for (int j = 0; j < 32; ++j) acc[j] = b1[o0 + j];
    #pragma unroll 2
    for (int c = 0; c < CHN; ++c) {
      const float h = Hs[c][lane];
      const float* wrow = W1t + c * CHN + o0;   // wave-uniform -> scalar loads
      #pragma unroll
      for (int j = 0; j < 32; ++j) acc[j] = fmaf(wrow[j], h, acc[j]);
    }
    #pragma unroll
    for (int j = 0; j < 32; ++j) Ys[o0 + j][lane] = fmaxf(acc[j], 0.0f);
    __syncthreads();
    #pragma unroll
    for (int j = 0; j < 32; ++j) acc[j] = b2[o0 + j];
    #pragma unroll 2
    for (int c = 0; c < CHN; ++c) {
      const float y = Ys[c][lane];
      const float* wrow = W2t + c * CHN + o0;
      #pragma unroll
      for (int j = 0; j < 32; ++j) acc[j] = fmaf(wrow[j], y, acc[j]);
    }
    #pragma unroll
    for (int j = 0; j < 32; ++j) {
      int o = o0 + j;
      Hs[o][lane] = fmaxf(Hs[o][lane] + acc[j], 0.0f);
    }
    __syncthreads();
  }

  // final 1x1 conv -> logit -> weight, then weighted Gram partials (this block's 64 pts)
  float part = 0.0f;
  #pragma unroll
  for (int j = 0; j < 32; ++j) part = fmaf(Wfinal[o0 + j], Hs[o0 + j][lane], part);
  red[wv][lane] = part;
  __syncthreads();
  if (wv == 0) {
    float logit = red[0][lane] + red[1][lane] + red[2][lane] + red[3][lane] + bfinal[0];
    float wgt = fmaxf(tanhf(logit), 0.0f);
    float X[9] = {y1 * x1, y1 * x2, y1, y2 * x1, y2 * x2, y2, x1, x2, 1.0f};
    int k = 0;
    #pragma unroll
    for (int i = 0; i < 9; ++i) {
      #pragma unroll
      for (int j = i; j < 9; ++j) {
        float v = wgt * X[i] * X[j];
        #pragma unroll
        for (int off = 32; off > 0; off >>= 1) v += __shfl_down(v, off, 64);
        if (lane == 0) partial[(size_t)blockIdx.x * 45 + k] = v;
        ++k;
      }
    }
  }
}

// ------------- deterministic fixed-order reduction of per-block partials -------------
__global__ void reduce_xwx_kernel(const float* __restrict__ partial,
                                  float* __restrict__ xwx) {
#pragma clang fp contract(off)
  int tid = blockIdx.x * 256 + threadIdx.x;
  if (tid >= 64 * 45) return;
  int b = tid / 45;
  int k = tid % 45;
  float s = 0.0f;
  for (int blk = 0; blk < 128; ++blk)
    s += partial[((size_t)b * 128 + blk) * 45 + k];
  xwx[tid] = s;
}

// -------- faithful LAPACK fp32 ssyevd path for 9x9 (ssytd2 + ssteqr('I') + Q) --------
__device__ inline float s_sign(float a, float b) { return (b >= 0.0f) ? fabsf(a) : -fabsf(a); }

__device__ inline float slapy2_(float x, float y) {
#pragma clang fp contract(off)
  float ax = fabsf(x), ay = fabsf(y);
  float w = ax > ay ? ax : ay;
  float z = ax > ay ? ay : ax;
  if (z == 0.0f) return w;
  float t = z / w;
  return w * sqrtf(1.0f + t * t);
}

// LAPACK >= 3.10 slartg (c >= 0 convention), fast path (magnitudes in range)
__device__ inline void slartg_(float f, float g, float* c, float* s, float* r) {
#pragma clang fp contract(off)
  if (g == 0.0f) { *c = 1.0f; *s = 0.0f; *r = f; }
  else if (f == 0.0f) { *c = 0.0f; *s = s_sign(1.0f, g); *r = fabsf(g); }
  else {
    float f1 = fabsf(f);
    float d = sqrtf(f * f + g * g);
    *c = f1 / d;
    *r = s_sign(d, f);
    *s = g / (*r);
  }
}

__device__ void slaev2_(float a, float b, float c, float* rt1, float* rt2,
                        float* cs1, float* sn1) {
#pragma clang fp contract(off)
  float sm = a + c, df = a - c, adf = fabsf(df), tb = b + b, ab = fabsf(tb);
  float acmx, acmn;
  if (fabsf(a) > fabsf(c)) { acmx = a; acmn = c; } else { acmx = c; acmn = a; }
  float rt;
  if (adf > ab) { float t = ab / adf; rt = adf * sqrtf(1.0f + t * t); }
  else if (adf < ab) { float t = adf / ab; rt = ab * sqrtf(1.0f + t * t); }
  else rt = ab * sqrtf(2.0f);
  int sgn1;
  if (sm < 0.0f) { *rt1 = 0.5f * (sm - rt); sgn1 = -1; *rt2 = (acmx / (*rt1)) * acmn - (b / (*rt1)) * b; }
  else if (sm > 0.0f) { *rt1 = 0.5f * (sm + rt); sgn1 = 1; *rt2 = (acmx / (*rt1)) * acmn - (b / (*rt1)) * b; }
  else { *rt1 = 0.5f * rt; *rt2 = -0.5f * rt; sgn1 = 1; }
  float cs; int sgn2;
  if (df >= 0.0f) { cs = df + rt; sgn2 = 1; } else { cs = df - rt; sgn2 = -1; }
  float acs = fabsf(cs);
  if (acs > ab) { float ct = -tb / cs; *sn1 = 1.0f / sqrtf(1.0f + ct * ct); *cs1 = ct * (*sn1); }
  else {
    if (ab == 0.0f) { *cs1 = 1.0f; *sn1 = 0.0f; }
    else { float tn = -cs / tb; *cs1 = 1.0f / sqrtf(1.0f + tn * tn); *sn1 = tn * (*cs1); }
  }
  if (sgn1 == sgn2) { float tn = *cs1; *cs1 = -(*sn1); *sn1 = tn; }
}

__global__ void eigen_kernel(const float* __restrict__ xwx, float* __restrict__ out) {
#pragma clang fp contract(off)
  __shared__ float A[81];
  __shared__ float Z[81];
  __shared__ float d1[10], e1[10], tauv[9], wc[10], wsn[10];
  if (threadIdx.x != 0) return;  // block-serial, LDS-resident
  const int b = blockIdx.x;
  const int n = 9;
  {
    int k = 0;
    for (int i = 0; i < 9; ++i)
      for (int j = i; j < 9; ++j, ++k) {
        float v = xwx[b * 45 + k];
        A[i * 9 + j] = v;
        A[j * 9 + i] = v;
      }
  }
  // --- ssytd2, UPLO='L' (fp32) ---
  for (int i = 0; i < n - 1; ++i) {
    float alpha = A[(i + 1) * 9 + i];
    float xn2 = 0.0f;
    for (int k2 = i + 2; k2 < n; ++k2) xn2 += A[k2 * 9 + i] * A[k2 * 9 + i];
    float xnorm = sqrtf(xn2);
    float taui;
    if (xnorm == 0.0f) taui = 0.0f;
    else {
      float beta = -s_sign(slapy2_(alpha, xnorm), alpha);
      taui = (beta - alpha) / beta;
      float scl = 1.0f / (alpha - beta);
      for (int k2 = i + 2; k2 < n; ++k2) A[k2 * 9 + i] *= scl;
      alpha = beta;
    }
    e1[i + 1] = alpha;
    if (taui != 0.0f) {
      float w[9];
      for (int r = i + 1; r < n; ++r) {
        float sum = A[r * 9 + (i + 1)];
        for (int k2 = i + 2; k2 < n; ++k2) sum += A[r * 9 + k2] * A[k2 * 9 + i];
        w[r] = taui * sum;
      }
      float wv_ = w[i + 1];
      for (int k2 = i + 2; k2 < n; ++k2) wv_ += w[k2] * A[k2 * 9 + i];
      float alpha2 = -0.5f * taui * wv_;
      for (int r = i + 1; r < n; ++r) w[r] += alpha2 * ((r == i + 1) ? 1.0f : A[r * 9 + i]);
      for (int r = i + 1; r < n; ++r) {
        float vr = (r == i + 1) ? 1.0f : A[r * 9 + i];
        for (int cc = i + 1; cc < n; ++cc) {
          float vc = (cc == i + 1) ? 1.0f : A[cc * 9 + i];
          A[r * 9 + cc] -= vr * w[cc] + w[r] * vc;
        }
      }
    }
    tauv[i] = taui;
  }
  for (int k2 = 0; k2 < n; ++k2) d1[k2 + 1] = A[k2 * 9 + k2];
  // --- ssteqr('I'): Z starts as identity (ssyevd/sstedc path for n<=smlsiz) ---
  for (int i = 0; i < 81; ++i) Z[i] = 0.0f;
  for (int i = 0; i < 9; ++i) Z[i * 9 + i] = 1.0f;
  const float eps = 5.9604645e-08f;          // slamch('E'), 2^-24
  const float eps2 = eps * eps;
  const float safmin = 1.17549435e-38f;      // slamch('S')
  const int nmaxit = n * 30;
  int jtot = 0;
  int l1 = 1;
  e1[9] = 0.0f;
  while (l1 <= n) {
    if (l1 > 1) e1[l1 - 1] = 0.0f;
    int m;
    if (l1 <= n - 1) {
      for (m = l1; m <= n - 1; ++m) {
        float tst = fabsf(e1[m]);
        if (tst == 0.0f) break;
        if (tst <= (sqrtf(fabsf(d1[m])) * sqrtf(fabsf(d1[m + 1]))) * eps) { e1[m] = 0.0f; break; }
      }
    } else m = n;
    int l = l1;
    int lsv = l, lend = m, lendsv = lend;
    l1 = m + 1;
    if (lend == l) continue;
    if (fabsf(d1[lend]) < fabsf(d1[l])) { lend = lsv; l = lendsv; }
    if (lend > l) {  // QL
      while (true) {
        int mq;
        if (l != lend) {
          for (mq = l; mq <= lend - 1; ++mq) {
            float tst = e1[mq] * e1[mq];
            if (tst <= (eps2 * fabsf(d1[mq])) * fabsf(d1[mq + 1]) + safmin) break;
          }
        } else mq = lend;
        if (mq < lend) e1[mq] = 0.0f;
        float p = d1[l];
        if (mq == l) { d1[l] = p; ++l; if (l <= lend) continue; break; }
        if (mq == l + 1) {
          float rt1, rt2, cq, sq;
          slaev2_(d1[l], e1[l], d1[l + 1], &rt1, &rt2, &cq, &sq);
          for (int i = 0; i < 9; ++i) {
            float t = Z[i * 9 + l];
            Z[i * 9 + l] = cq * t - sq * Z[i * 9 + l - 1];
            Z[i * 9 + l - 1] = sq * t + cq * Z[i * 9 + l - 1];
          }
          d1[l] = rt1; d1[l + 1] = rt2; e1[l] = 0.0f;
          l += 2;
          if (l <= lend) continue;
          break;
        }
        if (jtot == nmaxit) break;
        ++jtot;
        float g = (d1[l + 1] - p) / (2.0f * e1[l]);
        float r = slapy2_(g, 1.0f);
        g = d1[mq] - p + e1[l] / (g + s_sign(r, g));
        float sq = 1.0f, cq = 1.0f;
        p = 0.0f;
        for (int i = mq - 1; i >= l; --i) {
          float f = sq * e1[i];
          float bq = cq * e1[i];
          slartg_(g, f, &cq, &sq, &r);
          if (i != mq - 1) e1[i + 1] = r;
          g = d1[i + 1] - p;
          r = (d1[i] - g) * sq + 2.0f * cq * bq;
          p = sq * r;
          d1[i + 1] = g + p;
          g = cq * r - bq;
          wc[i] = cq;
          wsn[i] = -sq;
        }
        for (int jj = mq - 1; jj >= l; --jj) {  // slasr 'R','V','B'
          float cj = wc[jj], sj = wsn[jj];
          for (int i = 0; i < 9; ++i) {
            float t = Z[i * 9 + jj];
            Z[i * 9 + jj] = cj * t - sj * Z[i * 9 + jj - 1];
            Z[i * 9 + jj - 1] = sj * t + cj * Z[i * 9 + jj - 1];
          }
        }
        d1[l] -= p;
        e1[l] = g;
      }
    } else {  // QR
      while (true) {
        int mq;
        if (l != lend) {
          for (mq = l; mq >= lend + 1; --mq) {
            float tst = e1[mq - 1] * e1[mq - 1];
            if (tst <= (eps2 * fabsf(d1[mq])) * fabsf(d1[mq - 1]) + safmin) break;
          }
        } else mq = lend;
        if (mq > lend) e1[mq - 1] = 0.0f;
        float p = d1[l];
        if (mq == l) { d1[l] = p; --l; if (l >= lend) continue; break; }
        if (mq == l - 1) {
          float rt1, rt2, cq, sq;
          slaev2_(d1[l - 1], e1[l - 1], d1[l], &rt1, &rt2, &cq, &sq);
          for (int i = 0; i < 9; ++i) {
            float t = Z[i * 9 + l - 1];
            Z[i * 9 + l - 1] = cq * t - sq * Z[i * 9 + l - 2];
            Z[i * 9 + l - 2] = sq * t + cq * Z[i * 9 + l - 2];
          }
          d1[l - 1] = rt1; d1[l] = rt2; e1[l - 1] = 0.0f;
          l -= 2;
          if (l >= lend) continue;
          break;
        }
        if (jtot == nmaxit) break;
        ++jtot;
        float g = (d1[l - 1] - p) / (2.0f * e1[l - 1]);
        float r = slapy2_(g, 1.0f);
        g = d1[mq] - p + e1[l - 1] / (g + s_sign(r, g));
        float sq = 1.0f, cq = 1.0f;
        p = 0.0f;
        for (int i = mq; i <= l - 1; ++i) {
          float f = sq * e1[i];
          float bq = cq * e1[i];
          slartg_(g, f, &cq, &sq, &r);
          if (i != mq) e1[i - 1] = r;
          g = d1[i] - p;
          r = (d1[i + 1] - g) * sq + 2.0f * cq * bq;
          p = sq * r;
          d1[i] = g + p;
          g = cq * r - bq;
          wc[i] = cq;
          wsn[i] = sq;
        }
        for (int jj = mq; jj <= l - 1; ++jj) {  // slasr 'R','V','F'
          float cj = wc[jj], sj = wsn[jj];
          for (int i = 0; i < 9; ++i) {
            float t = Z[i * 9 + jj];
            Z[i * 9 + jj] = cj * t - sj * Z[i * 9 + jj - 1];
            Z[i * 9 + jj - 1] = sj * t + cj * Z[i * 9 + jj - 1];
          }
        }
        d1[l] -= p;
        e1[l - 1] = g;
      }
    }
  }
  // selection sort ascending, swap eigenvector columns (inside ssteqr)
  for (int ii = 2; ii <= n; ++ii) {
    int i = ii - 1, k = i;
    float p = d1[i];
    for (int j = ii; j <= n; ++j)
      if (d1[j] < p) { k = j; p = d1[j]; }
    if (k != i) {
      d1[k] = d1[i];
      d1[i] = p;
      for (int r = 0; r < 9; ++r) {
        float t = Z[r * 9 + (i - 1)];
        Z[r * 9 + (i - 1)] = Z[r * 9 + (k - 1)];
        Z[r * 9 + (k - 1)] = t;
      }
    }
  }
  // --- sormtr('L','L','N'): z0 := Q * Z[:,0] = H(0)..H(7) applied i=7..0 ---
  float z0[9];
  for (int i = 0; i < 9; ++i) z0[i] = Z[i * 9 + 0];
  for (int i = n - 2; i >= 0; --i) {
    float taui = tauv[i];
    if (taui == 0.0f) continue;
    float sum = z0[i + 1];
    for (int k2 = i + 2; k2 < n; ++k2) sum += A[k2 * 9 + i] * z0[k2];
    sum *= taui;
    z0[i + 1] -= sum;
    for (int k2 = i + 2; k2 < n; ++k2) z0[k2] -= A[k2 * 9 + i] * sum;
  }
  float nrm = 0.0f;
  for (int i = 0; i < 9; ++i) nrm += z0[i] * z0[i];
  float q = sqrtf(nrm);
  for (int i = 0; i < 9; ++i) out[b * 9 + i] = z0[i] / q;
}

extern "C" void kernel_launch(void* const* d_in, const int* in_sizes, int n_in,
                              void* d_out, int out_size, void* d_ws, size_t ws_size,
                              hipStream_t stream) {
  const float* xc     = (const float*)d_in[0];
  const float* Wfirst = (const float*)d_in[1];
  const float* bfirst = (const float*)d_in[2];
  const float* W1s    = (const float*)d_in[3];
  const float* b1s    = (const float*)d_in[4];
  const float* W2s    = (const float*)d_in[5];
  const float* b2s    = (const float*)d_in[6];
  const float* Wfinal = (const float*)d_in[7];
  const float* bfinal = (const float*)d_in[8];

  float* Wt      = (float*)d_ws;                 // 24*128*128 floats = 1.5 MB
  float* partial = Wt + 24 * 128 * 128;          // 8192*45 floats = 1.4 MB
  float* xwx     = partial + 8192 * 45;          // 64*45 floats

  transpose_w_kernel<<<(24 * 128 * 128 + 255) / 256, 256, 0, stream>>>(W1s, W2s, Wt);
  mlp_xwx_kernel<<<8192, 256, 0, stream>>>(xc, Wfirst, bfirst, Wt, b1s, b2s,
                                           Wfinal, bfinal, partial);
  reduce_xwx_kernel<<<(64 * 45 + 255) / 256, 256, 0, stream>>>(partial, xwx);
  eigen_kernel<<<64, 64, 0, stream>>>(xwx, (float*)d_out);
}

// Round 4
// 1858.049 us; speedup vs baseline: 3.2649x; 3.2649x over previous
//
#include <hip/hip_runtime.h>
#include <math.h>

#define NPTS 8192
#define CHN 128
#define NLAYER 12
#define LDH 136   // fp16 LDS row stride (128 + 8): 272 B = 16-B aligned, breaks bank aliasing

typedef __attribute__((ext_vector_type(8))) _Float16 f16x8;
typedef __attribute__((ext_vector_type(4))) float f32x4;

__device__ inline void split_f16(float x, _Float16* hi, _Float16* lo) {
  _Float16 h = (_Float16)x;            // RNE
  *hi = h;
  *lo = (_Float16)(x - (float)h);      // residual, |x-hi-lo| <= 2^-22 |x|
}

union U2h { unsigned int u; _Float16 f[2]; };
union U4h { uint2 u; _Float16 f[4]; };

// ---- split W1s/W2s fp32 -> (hi,lo) fp16; conv c = 2*layer (W1) / 2*layer+1 (W2), [o][c] ----
__global__ void prep_w_kernel(const float* __restrict__ W1s,
                              const float* __restrict__ W2s,
                              _Float16* __restrict__ Whi,
                              _Float16* __restrict__ Wlo) {
  int idx = blockIdx.x * 256 + threadIdx.x;
  if (idx >= 24 * 128 * 128) return;
  int conv = idx >> 14;
  int r = idx & 16383;
  const float* src = (conv & 1) ? (W2s + ((size_t)(conv >> 1) << 14))
                                : (W1s + ((size_t)(conv >> 1) << 14));
  _Float16 h, l;
  split_f16(src[r], &h, &l);
  Whi[idx] = h;
  Wlo[idx] = l;
}

// ---------------- MFMA MLP (fp16-split, fp32-grade) + weighted Gram partials ----------------
__global__ __launch_bounds__(256, 2) void mlp_xwx_kernel(
    const float* __restrict__ xc,            // (B,4,N)
    const float* __restrict__ Wfirst,        // (128,4) fp32
    const float* __restrict__ bfirst,        // (128)
    const _Float16* __restrict__ Whi,        // (24,128,128)
    const _Float16* __restrict__ Wlo,        // (24,128,128)
    const float* __restrict__ b1s,           // (12,128)
    const float* __restrict__ b2s,           // (12,128)
    const float* __restrict__ Wfinal,        // (128)
    const float* __restrict__ bfinal,        // (1)
    float* __restrict__ partial) {           // (8192,45)
  __shared__ __align__(16) _Float16 Hh[64 * LDH];
  __shared__ __align__(16) _Float16 Hl[64 * LDH];
  __shared__ __align__(16) _Float16 Yh[64 * LDH];
  __shared__ __align__(16) _Float16 Yl[64 * LDH];
  __shared__ float red[4][64];
  const int tid = threadIdx.x;
  const int lane = tid & 63;
  const int wv = tid >> 6;
  const int l16 = lane & 15;
  const int quad = lane >> 4;
  const int o0 = wv << 5;                 // wave's 32-channel base
  const int b = blockIdx.x >> 7;
  const int n0 = (blockIdx.x & 127) << 6;

  const float* xb = xc + ((size_t)b * 4) * NPTS + n0 + lane;
  const float x1 = xb[0 * NPTS];
  const float x2 = xb[1 * NPTS];
  const float y1 = xb[2 * NPTS];
  const float y2 = xb[3 * NPTS];

  // ---- first layer (4 -> 128) on VALU fp32, split to fp16 hi/lo H[p][c] ----
  {
    const int cg = wv << 5;
    #pragma unroll
    for (int j = 0; j < 32; j += 2) {
      int c = cg + j;
      float h0 = bfirst[c] + Wfirst[c * 4 + 0] * x1 + Wfirst[c * 4 + 1] * x2 +
                 Wfirst[c * 4 + 2] * y1 + Wfirst[c * 4 + 3] * y2;
      float h1 = bfirst[c + 1] + Wfirst[(c + 1) * 4 + 0] * x1 + Wfirst[(c + 1) * 4 + 1] * x2 +
                 Wfirst[(c + 1) * 4 + 2] * y1 + Wfirst[(c + 1) * 4 + 3] * y2;
      U2h ph, pl;
      split_f16(h0, &ph.f[0], &pl.f[0]);
      split_f16(h1, &ph.f[1], &pl.f[1]);
      *(unsigned int*)&Hh[lane * LDH + c] = ph.u;
      *(unsigned int*)&Hl[lane * LDH + c] = pl.u;
    }
  }
  __syncthreads();

  // A-frag base: W[o0 + l16 + 16*mt][quad*8 + 32*kt + j]
  const size_t arow = (size_t)(o0 + l16) * CHN + (size_t)quad * 8;

  for (int layer = 0; layer < NLAYER; ++layer) {
    // ===================== conv1: Y = relu(W1 H + b1) =====================
    {
      const _Float16* W1h = Whi + ((size_t)(2 * layer) << 14);
      const _Float16* W1l = Wlo + ((size_t)(2 * layer) << 14);
      const float* b1 = b1s + layer * CHN;
      f16x8 ah[2][4], al[2][4];
      #pragma unroll
      for (int mt = 0; mt < 2; ++mt)
        #pragma unroll
        for (int kt = 0; kt < 4; ++kt) {
          ah[mt][kt] = *(const f16x8*)(W1h + arow + (size_t)mt * 16 * CHN + kt * 32);
          al[mt][kt] = *(const f16x8*)(W1l + arow + (size_t)mt * 16 * CHN + kt * 32);
        }
      f32x4 acc[2][4];
      #pragma unroll
      for (int mt = 0; mt < 2; ++mt)
        #pragma unroll
        for (int r = 0; r < 4; ++r) {
          float bv = b1[o0 + mt * 16 + quad * 4 + r];
          #pragma unroll
          for (int nt = 0; nt < 4; ++nt) acc[mt][nt][r] = bv;
        }
      #pragma unroll
      for (int kt = 0; kt < 4; ++kt) {
        #pragma unroll
        for (int nt = 0; nt < 4; ++nt) {
          f16x8 bh = *(const f16x8*)&Hh[(nt * 16 + l16) * LDH + kt * 32 + quad * 8];
          f16x8 bl = *(const f16x8*)&Hl[(nt * 16 + l16) * LDH + kt * 32 + quad * 8];
          #pragma unroll
          for (int mt = 0; mt < 2; ++mt) {
            acc[mt][nt] = __builtin_amdgcn_mfma_f32_16x16x32_f16(ah[mt][kt], bh, acc[mt][nt], 0, 0, 0);
            acc[mt][nt] = __builtin_amdgcn_mfma_f32_16x16x32_f16(ah[mt][kt], bl, acc[mt][nt], 0, 0, 0);
            acc[mt][nt] = __builtin_amdgcn_mfma_f32_16x16x32_f16(al[mt][kt], bh, acc[mt][nt], 0, 0, 0);
          }
        }
      }
      #pragma unroll
      for (int mt = 0; mt < 2; ++mt)
        #pragma unroll
        for (int nt = 0; nt < 4; ++nt) {
          int p = nt * 16 + l16;
          int c = o0 + mt * 16 + quad * 4;
          U4h ph, pl;
          #pragma unroll
          for (int r = 0; r < 4; ++r) {
            float v = fmaxf(acc[mt][nt][r], 0.0f);
            split_f16(v, &ph.f[r], &pl.f[r]);
          }
          *(uint2*)&Yh[p * LDH + c] = ph.u;
          *(uint2*)&Yl[p * LDH + c] = pl.u;
        }
    }
    __syncthreads();
    // ===================== conv2: H = relu(H + W2 Y + b2) =====================
    {
      const _Float16* W2h = Whi + ((size_t)(2 * layer + 1) << 14);
      const _Float16* W2l = Wlo + ((size_t)(2 * layer + 1) << 14);
      const float* b2 = b2s + layer * CHN;
      f16x8 ah[2][4], al[2][4];
      #pragma unroll
      for (int mt = 0; mt < 2; ++mt)
        #pragma unroll
        for (int kt = 0; kt < 4; ++kt) {
          ah[mt][kt] = *(const f16x8*)(W2h + arow + (size_t)mt * 16 * CHN + kt * 32);
          al[mt][kt] = *(const f16x8*)(W2l + arow + (size_t)mt * 16 * CHN + kt * 32);
        }
      f32x4 acc[2][4];
      #pragma unroll
      for (int mt = 0; mt < 2; ++mt)
        #pragma unroll
        for (int r = 0; r < 4; ++r) {
          float bv = b2[o0 + mt * 16 + quad * 4 + r];
          #pragma unroll
          for (int nt = 0; nt < 4; ++nt) acc[mt][nt][r] = bv;
        }
      #pragma unroll
      for (int kt = 0; kt < 4; ++kt) {
        #pragma unroll
        for (int nt = 0; nt < 4; ++nt) {
          f16x8 bh = *(const f16x8*)&Yh[(nt * 16 + l16) * LDH + kt * 32 + quad * 8];
          f16x8 bl = *(const f16x8*)&Yl[(nt * 16 + l16) * LDH + kt * 32 + quad * 8];
          #pragma unroll
          for (int mt = 0; mt < 2; ++mt) {
            acc[mt][nt] = __builtin_amdgcn_mfma_f32_16x16x32_f16(ah[mt][kt], bh, acc[mt][nt], 0, 0, 0);
            acc[mt][nt] = __builtin_amdgcn_mfma_f32_16x16x32_f16(ah[mt][kt], bl, acc[mt][nt], 0, 0, 0);
            acc[mt][nt] = __builtin_amdgcn_mfma_f32_16x16x32_f16(al[mt][kt], bh, acc[mt][nt], 0, 0, 0);
          }
        }
      }
      #pragma unroll
      for (int mt = 0; mt < 2; ++mt)
        #pragma unroll
        for (int nt = 0; nt < 4; ++nt) {
          int p = nt * 16 + l16;
          int c = o0 + mt * 16 + quad * 4;
          U4h oh, ol;
          oh.u = *(const uint2*)&Hh[p * LDH + c];
          ol.u = *(const uint2*)&Hl[p * LDH + c];
          U4h ph, pl;
          #pragma unroll
          for (int r = 0; r < 4; ++r) {
            float hold = (float)oh.f[r] + (float)ol.f[r];
            float v = fmaxf(hold + acc[mt][nt][r], 0.0f);
            split_f16(v, &ph.f[r], &pl.f[r]);
          }
          *(uint2*)&Hh[p * LDH + c] = ph.u;
          *(uint2*)&Hl[p * LDH + c] = pl.u;
        }
    }
    __syncthreads();
  }

  // ---- final conv (128 -> 1): wave wv sums channels wv*32..+31 for point `lane` ----
  float part = 0.0f;
  #pragma unroll
  for (int j = 0; j < 4; ++j) {
    f16x8 kh = *(const f16x8*)&Hh[lane * LDH + (wv << 5) + j * 8];
    f16x8 kl = *(const f16x8*)&Hl[lane * LDH + (wv << 5) + j * 8];
    #pragma unroll
    for (int e = 0; e < 8; ++e)
      part = fmaf(Wfinal[(wv << 5) + j * 8 + e], (float)kh[e] + (float)kl[e], part);
  }
  red[wv][lane] = part;
  __syncthreads();
  if (wv == 0) {
    float logit = red[0][lane] + red[1][lane] + red[2][lane] + red[3][lane] + bfinal[0];
    float wgt = fmaxf(tanhf(logit), 0.0f);
    float X[9] = {y1 * x1, y1 * x2, y1, y2 * x1, y2 * x2, y2, x1, x2, 1.0f};
    int k = 0;
    #pragma unroll
    for (int i = 0; i < 9; ++i) {
      #pragma unroll
      for (int j = i; j < 9; ++j) {
        float v = wgt * X[i] * X[j];
        #pragma unroll
        for (int off = 32; off > 0; off >>= 1) v += __shfl_down(v, off, 64);
        if (lane == 0) partial[(size_t)blockIdx.x * 45 + k] = v;
        ++k;
      }
    }
  }
}

// ------------- deterministic fixed-order reduction of per-block partials -------------
__global__ void reduce_xwx_kernel(const float* __restrict__ partial,
                                  float* __restrict__ xwx) {
#pragma clang fp contract(off)
  int tid = blockIdx.x * 256 + threadIdx.x;
  if (tid >= 64 * 45) return;
  int b = tid / 45;
  int k = tid % 45;
  float s = 0.0f;
  for (int blk = 0; blk < 128; ++blk)
    s += partial[((size_t)b * 128 + blk) * 45 + k];
  xwx[tid] = s;
}

// -------- faithful LAPACK fp32 ssyevd path for 9x9 (ssytd2 + ssteqr('I') + Q) --------
__device__ inline float s_sign(float a, float b) { return (b >= 0.0f) ? fabsf(a) : -fabsf(a); }

__device__ inline float slapy2_(float x, float y) {
#pragma clang fp contract(off)
  float ax = fabsf(x), ay = fabsf(y);
  float w = ax > ay ? ax : ay;
  float z = ax > ay ? ay : ax;
  if (z == 0.0f) return w;
  float t = z / w;
  return w * sqrtf(1.0f + t * t);
}

// LAPACK >= 3.10 slartg (c >= 0 convention), fast path
__device__ inline void slartg_(float f, float g, float* c, float* s, float* r) {
#pragma clang fp contract(off)
  if (g == 0.0f) { *c = 1.0f; *s = 0.0f; *r = f; }
  else if (f == 0.0f) { *c = 0.0f; *s = s_sign(1.0f, g); *r = fabsf(g); }
  else {
    float f1 = fabsf(f);
    float d = sqrtf(f * f + g * g);
    *c = f1 / d;
    *r = s_sign(d, f);
    *s = g / (*r);
  }
}

__device__ void slaev2_(float a, float b, float c, float* rt1, float* rt2,
                        float* cs1, float* sn1) {
#pragma clang fp contract(off)
  float sm = a + c, df = a - c, adf = fabsf(df), tb = b + b, ab = fabsf(tb);
  float acmx, acmn;
  if (fabsf(a) > fabsf(c)) { acmx = a; acmn = c; } else { acmx = c; acmn = a; }
  float rt;
  if (adf > ab) { float t = ab / adf; rt = adf * sqrtf(1.0f + t * t); }
  else if (adf < ab) { float t = adf / ab; rt = ab * sqrtf(1.0f + t * t); }
  else rt = ab * sqrtf(2.0f);
  int sgn1;
  if (sm < 0.0f) { *rt1 = 0.5f * (sm - rt); sgn1 = -1; *rt2 = (acmx / (*rt1)) * acmn - (b / (*rt1)) * b; }
  else if (sm > 0.0f) { *rt1 = 0.5f * (sm + rt); sgn1 = 1; *rt2 = (acmx / (*rt1)) * acmn - (b / (*rt1)) * b; }
  else { *rt1 = 0.5f * rt; *rt2 = -0.5f * rt; sgn1 = 1; }
  float cs; int sgn2;
  if (df >= 0.0f) { cs = df + rt; sgn2 = 1; } else { cs = df - rt; sgn2 = -1; }
  float acs = fabsf(cs);
  if (acs > ab) { float ct = -tb / cs; *sn1 = 1.0f / sqrtf(1.0f + ct * ct); *cs1 = ct * (*sn1); }
  else {
    if (ab == 0.0f) { *cs1 = 1.0f; *sn1 = 0.0f; }
    else { float tn = -cs / tb; *cs1 = 1.0f / sqrtf(1.0f + tn * tn); *sn1 = tn * (*cs1); }
  }
  if (sgn1 == sgn2) { float tn = *cs1; *cs1 = -(*sn1); *sn1 = tn; }
}

__global__ void eigen_kernel(const float* __restrict__ xwx, float* __restrict__ out) {
#pragma clang fp contract(off)
  __shared__ float A[81];
  __shared__ float Z[81];
  __shared__ float d1[10], e1[10], tauv[9], wc[10], wsn[10];
  if (threadIdx.x != 0) return;
  const int b = blockIdx.x;
  const int n = 9;
  {
    int k = 0;
    for (int i = 0; i < 9; ++i)
      for (int j = i; j < 9; ++j, ++k) {
        float v = xwx[b * 45 + k];
        A[i * 9 + j] = v;
        A[j * 9 + i] = v;
      }
  }
  for (int i = 0; i < n - 1; ++i) {
    float alpha = A[(i + 1) * 9 + i];
    float xn2 = 0.0f;
    for (int k2 = i + 2; k2 < n; ++k2) xn2 += A[k2 * 9 + i] * A[k2 * 9 + i];
    float xnorm = sqrtf(xn2);
    float taui;
    if (xnorm == 0.0f) taui = 0.0f;
    else {
      float beta = -s_sign(slapy2_(alpha, xnorm), alpha);
      taui = (beta - alpha) / beta;
      float scl = 1.0f / (alpha - beta);
      for (int k2 = i + 2; k2 < n; ++k2) A[k2 * 9 + i] *= scl;
      alpha = beta;
    }
    e1[i + 1] = alpha;
    if (taui != 0.0f) {
      float w[9];
      for (int r = i + 1; r < n; ++r) {
        float sum = A[r * 9 + (i + 1)];
        for (int k2 = i + 2; k2 < n; ++k2) sum += A[r * 9 + k2] * A[k2 * 9 + i];
        w[r] = taui * sum;
      }
      float wv_ = w[i + 1];
      for (int k2 = i + 2; k2 < n; ++k2) wv_ += w[k2] * A[k2 * 9 + i];
      float alpha2 = -0.5f * taui * wv_;
      for (int r = i + 1; r < n; ++r) w[r] += alpha2 * ((r == i + 1) ? 1.0f : A[r * 9 + i]);
      for (int r = i + 1; r < n; ++r) {
        float vr = (r == i + 1) ? 1.0f : A[r * 9 + i];
        for (int cc = i + 1; cc < n; ++cc) {
          float vc = (cc == i + 1) ? 1.0f : A[cc * 9 + i];
          A[r * 9 + cc] -= vr * w[cc] + w[r] * vc;
        }
      }
    }
    tauv[i] = taui;
  }
  for (int k2 = 0; k2 < n; ++k2) d1[k2 + 1] = A[k2 * 9 + k2];
  for (int i = 0; i < 81; ++i) Z[i] = 0.0f;
  for (int i = 0; i < 9; ++i) Z[i * 9 + i] = 1.0f;
  const float eps = 5.9604645e-08f;
  const float eps2 = eps * eps;
  const float safmin = 1.17549435e-38f;
  const int nmaxit = n * 30;
  int jtot = 0;
  int l1 = 1;
  e1[9] = 0.0f;
  while (l1 <= n) {
    if (l1 > 1) e1[l1 - 1] = 0.0f;
    int m;
    if (l1 <= n - 1) {
      for (m = l1; m <= n - 1; ++m) {
        float tst = fabsf(e1[m]);
        if (tst == 0.0f) break;
        if (tst <= (sqrtf(fabsf(d1[m])) * sqrtf(fabsf(d1[m + 1]))) * eps) { e1[m] = 0.0f; break; }
      }
    } else m = n;
    int l = l1;
    int lsv = l, lend = m, lendsv = lend;
    l1 = m + 1;
    if (lend == l) continue;
    if (fabsf(d1[lend]) < fabsf(d1[l])) { lend = lsv; l = lendsv; }
    if (lend > l) {
      while (true) {
        int mq;
        if (l != lend) {
          for (mq = l; mq <= lend - 1; ++mq) {
            float tst = e1[mq] * e1[mq];
            if (tst <= (eps2 * fabsf(d1[mq])) * fabsf(d1[mq + 1]) + safmin) break;
          }
        } else mq = lend;
        if (mq < lend) e1[mq] = 0.0f;
        float p = d1[l];
        if (mq == l) { d1[l] = p; ++l; if (l <= lend) continue; break; }
        if (mq == l + 1) {
          float rt1, rt2, cq, sq;
          slaev2_(d1[l], e1[l], d1[l + 1], &rt1, &rt2, &cq, &sq);
          for (int i = 0; i < 9; ++i) {
            float t = Z[i * 9 + l];
            Z[i * 9 + l] = cq * t - sq * Z[i * 9 + l - 1];
            Z[i * 9 + l - 1] = sq * t + cq * Z[i * 9 + l - 1];
          }
          d1[l] = rt1; d1[l + 1] = rt2; e1[l] = 0.0f;
          l += 2;
          if (l <= lend) continue;
          break;
        }
        if (jtot == nmaxit) break;
        ++jtot;
        float g = (d1[l + 1] - p) / (2.0f * e1[l]);
        float r = slapy2_(g, 1.0f);
        g = d1[mq] - p + e1[l] / (g + s_sign(r, g));
        float sq = 1.0f, cq = 1.0f;
        p = 0.0f;
        for (int i = mq - 1; i >= l; --i) {
          float f = sq * e1[i];
          float bq = cq * e1[i];
          slartg_(g, f, &cq, &sq, &r);
          if (i != mq - 1) e1[i + 1] = r;
          g = d1[i + 1] - p;
          r = (d1[i] - g) * sq + 2.0f * cq * bq;
          p = sq * r;
          d1[i + 1] = g + p;
          g = cq * r - bq;
          wc[i] = cq;
          wsn[i] = -sq;
        }
        for (int jj = mq - 1; jj >= l; --jj) {
          float cj = wc[jj], sj = wsn[jj];
          for (int i = 0; i < 9; ++i) {
            float t = Z[i * 9 + jj];
            Z[i * 9 + jj] = cj * t - sj * Z[i * 9 + jj - 1];
            Z[i * 9 + jj - 1] = sj * t + cj * Z[i * 9 + jj - 1];
          }
        }
        d1[l] -= p;
        e1[l] = g;
      }
    } else {
      while (true) {
        int mq;
        if (l != lend) {
          for (mq = l; mq >= lend + 1; --mq) {
            float tst = e1[mq - 1] * e1[mq - 1];
            if (tst <= (eps2 * fabsf(d1[mq])) * fabsf(d1[mq - 1]) + safmin) break;
          }
        } else mq = lend;
        if (mq > lend) e1[mq - 1] = 0.0f;
        float p = d1[l];
        if (mq == l) { d1[l] = p; --l; if (l >= lend) continue; break; }
        if (mq == l - 1) {
          float rt1, rt2, cq, sq;
          slaev2_(d1[l - 1], e1[l - 1], d1[l], &rt1, &rt2, &cq, &sq);
          for (int i = 0; i < 9; ++i) {
            float t = Z[i * 9 + l - 1];
            Z[i * 9 + l - 1] = cq * t - sq * Z[i * 9 + l - 2];
            Z[i * 9 + l - 2] = sq * t + cq * Z[i * 9 + l - 2];
          }
          d1[l - 1] = rt1; d1[l] = rt2; e1[l - 1] = 0.0f;
          l -= 2;
          if (l >= lend) continue;
          break;
        }
        if (jtot == nmaxit) break;
        ++jtot;
        float g = (d1[l - 1] - p) / (2.0f * e1[l - 1]);
        float r = slapy2_(g, 1.0f);
        g = d1[mq] - p + e1[l - 1] / (g + s_sign(r, g));
        float sq = 1.0f, cq = 1.0f;
        p = 0.0f;
        for (int i = mq; i <= l - 1; ++i) {
          float f = sq * e1[i];
          float bq = cq * e1[i];
          slartg_(g, f, &cq, &sq, &r);
          if (i != mq) e1[i - 1] = r;
          g = d1[i] - p;
          r = (d1[i + 1] - g) * sq + 2.0f * cq * bq;
          p = sq * r;
          d1[i] = g + p;
          g = cq * r - bq;
          wc[i] = cq;
          wsn[i] = sq;
        }
        for (int jj = mq; jj <= l - 1; ++jj) {
          float cj = wc[jj], sj = wsn[jj];
          for (int i = 0; i < 9; ++i) {
            float t = Z[i * 9 + jj];
            Z[i * 9 + jj] = cj * t - sj * Z[i * 9 + jj - 1];
            Z[i * 9 + jj - 1] = sj * t + cj * Z[i * 9 + jj - 1];
          }
        }
        d1[l] -= p;
        e1[l - 1] = g;
      }
    }
  }
  for (int ii = 2; ii <= n; ++ii) {
    int i = ii - 1, k = i;
    float p = d1[i];
    for (int j = ii; j <= n; ++j)
      if (d1[j] < p) { k = j; p = d1[j]; }
    if (k != i) {
      d1[k] = d1[i];
      d1[i] = p;
      for (int r = 0; r < 9; ++r) {
        float t = Z[r * 9 + (i - 1)];
        Z[r * 9 + (i - 1)] = Z[r * 9 + (k - 1)];
        Z[r * 9 + (k - 1)] = t;
      }
    }
  }
  float z0[9];
  for (int i = 0; i < 9; ++i) z0[i] = Z[i * 9 + 0];
  for (int i = n - 2; i >= 0; --i) {
    float taui = tauv[i];
    if (taui == 0.0f) continue;
    float sum = z0[i + 1];
    for (int k2 = i + 2; k2 < n; ++k2) sum += A[k2 * 9 + i] * z0[k2];
    sum *= taui;
    z0[i + 1] -= sum;
    for (int k2 = i + 2; k2 < n; ++k2) z0[k2] -= A[k2 * 9 + i] * sum;
  }
  float nrm = 0.0f;
  for (int i = 0; i < 9; ++i) nrm += z0[i] * z0[i];
  float q = sqrtf(nrm);
  for (int i = 0; i < 9; ++i) out[b * 9 + i] = z0[i] / q;
}

extern "C" void kernel_launch(void* const* d_in, const int* in_sizes, int n_in,
                              void* d_out, int out_size, void* d_ws, size_t ws_size,
                              hipStream_t stream) {
  const float* xc     = (const float*)d_in[0];
  const float* Wfirst = (const float*)d_in[1];
  const float* bfirst = (const float*)d_in[2];
  const float* W1s    = (const float*)d_in[3];
  const float* b1s    = (const float*)d_in[4];
  const float* W2s    = (const float*)d_in[5];
  const float* b2s    = (const float*)d_in[6];
  const float* Wfinal = (const float*)d_in[7];
  const float* bfinal = (const float*)d_in[8];

  _Float16* Whi = (_Float16*)d_ws;                       // 24*16384 = 768 KB
  _Float16* Wlo = Whi + (size_t)24 * 128 * 128;          // 768 KB
  float* partial = (float*)(Wlo + (size_t)24 * 128 * 128);  // 8192*45*4 = 1.47 MB
  float* xwx = partial + (size_t)8192 * 45;

  prep_w_kernel<<<(24 * 128 * 128 + 255) / 256, 256, 0, stream>>>(W1s, W2s, Whi, Wlo);
  mlp_xwx_kernel<<<8192, 256, 0, stream>>>(xc, Wfirst, bfirst, Whi, Wlo, b1s, b2s,
                                           Wfinal, bfinal, partial);
  reduce_xwx_kernel<<<(64 * 45 + 255) / 256, 256, 0, stream>>>(partial, xwx);
  eigen_kernel<<<64, 64, 0, stream>>>(xwx, (float*)d_out);
}